// Round 7
// baseline (559.224 us; speedup 1.0000x reference)
//
#include <hip/hip_runtime.h>
#include <hip/hip_bf16.h>
#include <cstdint>

#define HID 512
#define K1P 288   // feat K padded 272 -> 288

typedef __attribute__((ext_vector_type(8))) short bf16x8;
typedef __attribute__((ext_vector_type(4))) float f32x4;

__device__ __forceinline__ short f2bf(float x) {
    __hip_bfloat16 h = __float2bfloat16(x);
    return *(short*)&h;
}
__device__ __forceinline__ float bf2f(short s) {
    unsigned u = ((unsigned)(unsigned short)s) << 16;
    float f; __builtin_memcpy(&f, &u, 4); return f;
}
__device__ __forceinline__ float silu(float x) {
    return x * (1.0f / (1.0f + __expf(-x)));
}
__device__ __forceinline__ void gl_lds16(const void* src, void* dst) {
    __builtin_amdgcn_global_load_lds(
        (const __attribute__((address_space(1))) void*)src,
        (__attribute__((address_space(3))) void*)dst, 16, 0, 0);
}

// ---------- 1) histogram ----------
__global__ __launch_bounds__(256) void hist_kernel(
    const int* __restrict__ idx, int* __restrict__ counts, int nEdges)
{
    int e = blockIdx.x * 256 + threadIdx.x;
    if (e < nEdges) atomicAdd(&counts[idx[e]], 1);
}

// ---------- 2) scan, pass 1 ----------
__global__ __launch_bounds__(1024) void scan1_kernel(
    const int* __restrict__ counts, int* __restrict__ starts,
    int* __restrict__ blockSum, int n)
{
    __shared__ int wsum[16];
    int t = threadIdx.x, lane = t & 63, wid = t >> 6;
    int i = blockIdx.x * 1024 + t;
    int v = (i < n) ? counts[i] : 0;
    int incl = v;
    #pragma unroll
    for (int off = 1; off < 64; off <<= 1) {
        int u = __shfl_up(incl, off);
        if (lane >= off) incl += u;
    }
    if (lane == 63) wsum[wid] = incl;
    __syncthreads();
    if (t < 16) {
        int s = wsum[t];
        #pragma unroll
        for (int off = 1; off < 16; off <<= 1) {
            int u = __shfl_up(s, off);
            if (t >= off) s += u;
        }
        wsum[t] = s;
    }
    __syncthreads();
    int woff = (wid == 0) ? 0 : wsum[wid - 1];
    if (i < n) starts[i] = woff + incl - v;
    if (t == 0) blockSum[blockIdx.x] = wsum[15];
}

// ---------- 2b) scan block sums ----------
__global__ __launch_bounds__(1024) void scan2_kernel(
    const int* __restrict__ blockSum, int* __restrict__ blockOff,
    int* __restrict__ starts, int nb, int n)
{
    __shared__ int arr[1024];
    int t = threadIdx.x;
    int v = (t < nb) ? blockSum[t] : 0;
    arr[t] = v;
    __syncthreads();
    #pragma unroll
    for (int off = 1; off < 1024; off <<= 1) {
        int x = (t >= off) ? arr[t - off] : 0;
        __syncthreads();
        arr[t] += x;
        __syncthreads();
    }
    if (t < nb) blockOff[t] = arr[t] - v;
    if (t == 0) starts[n] = arr[nb - 1];
}

// ---------- 2c) add offsets ----------
__global__ __launch_bounds__(1024) void scan3_kernel(
    int* __restrict__ starts, int* __restrict__ cursor,
    const int* __restrict__ blockOff, int n)
{
    int i = blockIdx.x * 1024 + threadIdx.x;
    if (i < n) {
        int s = starts[i] + blockOff[blockIdx.x];
        starts[i] = s;
        cursor[i] = s;
    }
}

// ---------- 3) scatter ----------
__global__ __launch_bounds__(256) void scatter_kernel(
    const float* __restrict__ R, const int* __restrict__ idx,
    int* __restrict__ cursor, float4* __restrict__ sorted, int nEdges)
{
    int e = blockIdx.x * 256 + threadIdx.x;
    if (e >= nEdges) return;
    int i = idx[e];
    int j = idx[nEdges + e];
    float rix = R[3*(size_t)i], riy = R[3*(size_t)i+1], riz = R[3*(size_t)i+2];
    float rjx = R[3*(size_t)j], rjy = R[3*(size_t)j+1], rjz = R[3*(size_t)j+2];
    float dx = rjx - rix, dy = rjy - riy, dz = rjz - riz;
    float r = sqrtf(dx*dx + dy*dy + dz*dz);
    float inv = 1.0f / (r + 1e-8f);
    int pos = atomicAdd(&cursor[i], 1);
    sorted[pos] = make_float4(r, dx*inv, dy*inv, dz*inv);
}

// ---------- 4) segmented reduce ----------
__global__ __launch_bounds__(256) void accum_kernel(
    const float4* __restrict__ sorted, const int* __restrict__ starts,
    const float* __restrict__ centers, const float* __restrict__ width,
    float* __restrict__ M0M1, int nAtoms)
{
    int wv = threadIdx.x >> 6, lane = threadIdx.x & 63;
    int atom = blockIdx.x * 4 + wv;
    if (atom >= nAtoms) return;
    int s = starts[atom], e = starts[atom + 1];
    int k = lane >> 2, c = lane & 3;
    float ck = centers[k];
    float w = width[0];
    float inv2w2 = 1.0f / (2.0f * w * w);
    float acc = 0.0f;
    for (int p = s; p < e; ++p) {
        float4 v = sorted[p];
        float diff = v.x - ck;
        float b = __expf(-diff * diff * inv2w2);
        float comp = (c == 0) ? 1.0f : ((c == 1) ? v.y : ((c == 2) ? v.z : v.w));
        acc += b * comp;
    }
    M0M1[(size_t)atom * 64 + lane] = acc;
}

// ---------- W -> bf16 transposed ----------
__global__ __launch_bounds__(256) void convW_kernel(
    const float* __restrict__ W, short* __restrict__ Wt, int K, int Kpad, int N)
{
    int n = blockIdx.x * 256 + threadIdx.x;
    int k = blockIdx.y;
    if (n >= N) return;
    float v = (k < K) ? W[(size_t)k * N + n] : 0.0f;
    Wt[(size_t)n * Kpad + k] = f2bf(v);
}

// ---------- GEMM1 MFMA 128x256, counted-vmcnt pipeline ----------
__global__ __launch_bounds__(512) void gemm1_mfma(
    const float* __restrict__ M0M1, const short* __restrict__ W1t,
    const float* __restrict__ bias, short* __restrict__ C, int M)
{
    __shared__ short MsT[64][128];        // bf16 transposed M0M1, 16KB
    __shared__ short Asl[2][4 * 128 * 8]; // 2x8KB (ds_write staged)
    __shared__ short Bsl[3][4 * 256 * 8]; // 3x16KB (gl_lds staged)
    int t = threadIdx.x;
    int w = t >> 6, lane = t & 63;
    int wr = w >> 2, wc = w & 3;          // 2x4 wave grid: 64 rows x 64 cols
    int li = lane & 15, lg = lane >> 4;
    int row0 = blockIdx.x * 128;
    int col0 = blockIdx.y * 256;

    // stage M0M1 transposed into LDS as bf16
    {
        int mrow = t >> 2, mo = (t & 3) * 16;
        int gm = row0 + mrow; if (gm > M - 1) gm = M - 1;
        const float4* src = (const float4*)(M0M1 + (size_t)gm * 64 + mo);
        #pragma unroll
        for (int q = 0; q < 4; ++q) {
            float4 v = src[q];
            int c0 = mo + q * 4;
            MsT[c0+0][mrow] = f2bf(v.x); MsT[c0+1][mrow] = f2bf(v.y);
            MsT[c0+2][mrow] = f2bf(v.z); MsT[c0+3][mrow] = f2bf(v.w);
        }
    }
    __syncthreads();

    auto stageA = [&](int buf, int k0) {   // feat compute -> ds_write (lgkmcnt)
        int k8 = t >> 7, row = t & 127;
        int kbase = k0 + k8 * 8;
        bf16x8 v;
        if (kbase < 16) {
            #pragma unroll
            for (int j = 0; j < 8; ++j) v[j] = MsT[4*(kbase+j)][row];
        } else if (kbase < 272) {
            int g = kbase - 16, a = g >> 4, b0 = g & 15;
            float ax = bf2f(MsT[4*a+1][row]), ay = bf2f(MsT[4*a+2][row]), az = bf2f(MsT[4*a+3][row]);
            #pragma unroll
            for (int j = 0; j < 8; ++j) {
                int b = b0 + j;
                v[j] = f2bf(ax*bf2f(MsT[4*b+1][row]) + ay*bf2f(MsT[4*b+2][row]) + az*bf2f(MsT[4*b+3][row]));
            }
        } else {
            #pragma unroll
            for (int j = 0; j < 8; ++j) v[j] = 0;
        }
        *(bf16x8*)&Asl[buf][t * 8] = v;
    };
    auto stageB = [&](int buf, int k0) {   // 2 gl_lds per wave (vmcnt)
        #pragma unroll
        for (int p = 0; p < 2; ++p) {
            int cell = (w * 2 + p) * 64 + lane;
            int k8 = cell >> 8, n = cell & 255;
            const short* src = W1t + (size_t)(col0 + n) * K1P + k0 + k8 * 8;
            gl_lds16(src, &Bsl[buf][(w * 2 + p) * 64 * 8]);
        }
    };

    f32x4 zz = {0.f, 0.f, 0.f, 0.f};
    f32x4 acc[4][4];
    #pragma unroll
    for (int m = 0; m < 4; ++m)
        #pragma unroll
        for (int n = 0; n < 4; ++n) acc[m][n] = zz;

    const int NSTEP = K1P / 32;   // 9
    stageA(0, 0);
    stageB(0, 0); stageB(1, 32);  // 4 vmem in flight

    for (int s = 0; s < NSTEP; ++s) {
        // wait: tile s's B loads done (tile s+1 stays in flight) + own ds_writes drained
        if (s < NSTEP - 1) asm volatile("s_waitcnt vmcnt(2) lgkmcnt(0)\n\ts_barrier" ::: "memory");
        else               asm volatile("s_waitcnt vmcnt(0) lgkmcnt(0)\n\ts_barrier" ::: "memory");
        if (s + 2 < NSTEP) stageB((s + 2) % 3, (s + 2) * 32);
        bf16x8 af[4], bfr[4];
        const short* Ab = &Asl[s & 1][(lg * 128 + wr * 64 + li) * 8];
        const short* Bb = &Bsl[s % 3][(lg * 256 + wc * 64 + li) * 8];
        #pragma unroll
        for (int m = 0; m < 4; ++m) af[m] = *(const bf16x8*)(Ab + m * 128);
        #pragma unroll
        for (int n = 0; n < 4; ++n) bfr[n] = *(const bf16x8*)(Bb + n * 128);
        if (s + 1 < NSTEP) stageA((s + 1) & 1, (s + 1) * 32);
        #pragma unroll
        for (int m = 0; m < 4; ++m)
            #pragma unroll
            for (int n = 0; n < 4; ++n)
                acc[m][n] = __builtin_amdgcn_mfma_f32_16x16x32_bf16(af[m], bfr[n], acc[m][n], 0, 0, 0);
    }

    float bv[4];
    #pragma unroll
    for (int n = 0; n < 4; ++n) bv[n] = bias[col0 + wc * 64 + n * 16 + li];
    #pragma unroll
    for (int m = 0; m < 4; ++m)
        #pragma unroll
        for (int r = 0; r < 4; ++r) {
            int row = row0 + wr * 64 + m * 16 + lg * 4 + r;
            if (row >= M) continue;
            size_t base = (size_t)row * HID + col0 + wc * 64 + li;
            #pragma unroll
            for (int n = 0; n < 4; ++n) {
                float cx = acc[m][n][r] + bv[n];
                C[base + n * 16] = f2bf(silu(cx));
            }
        }
}

// ---------- GEMM2 MFMA 128x256, counted-vmcnt pipeline + fused energy epilogue ----------
__global__ __launch_bounds__(512) void gemm2_mfma(
    const short* __restrict__ A, const short* __restrict__ W2t,
    const float* __restrict__ bias, const float* __restrict__ W3,
    const float* __restrict__ b3, const float* __restrict__ scale,
    const float* __restrict__ shift, const int* __restrict__ Z,
    float* __restrict__ out, int M)
{
    __shared__ short Asl[3][4 * 128 * 8]; // 3x8KB
    __shared__ short Bsl[3][4 * 256 * 8]; // 3x16KB
    __shared__ float rsum[4][128];
    __shared__ float red[2];
    int t = threadIdx.x;
    int w = t >> 6, lane = t & 63;
    int wr = w >> 2, wc = w & 3;
    int li = lane & 15, lg = lane >> 4;
    int row0 = blockIdx.x * 128;
    int col0 = blockIdx.y * 256;

    auto stage = [&](int buf, int k0) {   // 3 gl_lds per wave per tile
        {
            int k8 = w >> 1, row = (w & 1) * 64 + lane;
            int gr = row0 + row; if (gr > M - 1) gr = M - 1;
            const short* src = A + (size_t)gr * HID + k0 + k8 * 8;
            gl_lds16(src, &Asl[buf][w * 64 * 8]);
        }
        #pragma unroll
        for (int p = 0; p < 2; ++p) {
            int cell = (w * 2 + p) * 64 + lane;
            int k8 = cell >> 8, n = cell & 255;
            const short* src = W2t + (size_t)(col0 + n) * HID + k0 + k8 * 8;
            gl_lds16(src, &Bsl[buf][(w * 2 + p) * 64 * 8]);
        }
    };

    f32x4 zz = {0.f, 0.f, 0.f, 0.f};
    f32x4 acc[4][4];
    #pragma unroll
    for (int m = 0; m < 4; ++m)
        #pragma unroll
        for (int n = 0; n < 4; ++n) acc[m][n] = zz;

    const int NSTEP = HID / 32;   // 16
    stage(0, 0); stage(1, 32);    // 6 vmem in flight

    for (int s = 0; s < NSTEP; ++s) {
        // wait: tile s done; tile s+1's 3 loads stay in flight
        if (s < NSTEP - 1) asm volatile("s_waitcnt vmcnt(3)\n\ts_barrier" ::: "memory");
        else               asm volatile("s_waitcnt vmcnt(0)\n\ts_barrier" ::: "memory");
        if (s + 2 < NSTEP) stage((s + 2) % 3, (s + 2) * 32);
        bf16x8 af[4], bfr[4];
        const short* Ab = &Asl[s % 3][(lg * 128 + wr * 64 + li) * 8];
        const short* Bb = &Bsl[s % 3][(lg * 256 + wc * 64 + li) * 8];
        #pragma unroll
        for (int m = 0; m < 4; ++m) af[m] = *(const bf16x8*)(Ab + m * 128);
        #pragma unroll
        for (int n = 0; n < 4; ++n) bfr[n] = *(const bf16x8*)(Bb + n * 128);
        #pragma unroll
        for (int m = 0; m < 4; ++m)
            #pragma unroll
            for (int n = 0; n < 4; ++n)
                acc[m][n] = __builtin_amdgcn_mfma_f32_16x16x32_bf16(af[m], bfr[n], acc[m][n], 0, 0, 0);
    }

    float bv[4], w3v[4];
    #pragma unroll
    for (int n = 0; n < 4; ++n) {
        int col = col0 + wc * 64 + n * 16 + li;
        bv[n] = bias[col];
        w3v[n] = W3[col];
    }
    #pragma unroll
    for (int m = 0; m < 4; ++m)
        #pragma unroll
        for (int r = 0; r < 4; ++r) {
            float s = 0.f;
            #pragma unroll
            for (int n = 0; n < 4; ++n) {
                float cx = acc[m][n][r] + bv[n];
                s += silu(cx) * w3v[n];
            }
            #pragma unroll
            for (int off = 1; off < 16; off <<= 1) s += __shfl_xor(s, off);
            if (li == 0) rsum[wc][wr * 64 + m * 16 + lg * 4 + r] = s;
        }
    __syncthreads();
    float e = 0.f;
    if (t < 128) {
        int row = row0 + t;
        if (row < M) {
            float v = rsum[0][t] + rsum[1][t] + rsum[2][t] + rsum[3][t];
            int z = Z[row];
            e = scale[z] * v;
            if (blockIdx.y == 0) e += scale[z] * b3[0] + shift[z];
        }
        #pragma unroll
        for (int off = 32; off > 0; off >>= 1) e += __shfl_down(e, off);
        if ((t & 63) == 0) red[t >> 6] = e;
    }
    __syncthreads();
    if (t == 0) atomicAdd(out, red[0] + red[1]);
}

extern "C" void kernel_launch(void* const* d_in, const int* in_sizes, int n_in,
                              void* d_out, int out_size, void* d_ws, size_t ws_size,
                              hipStream_t stream)
{
    const float* R       = (const float*)d_in[0];
    const int*   Z       = (const int*)  d_in[1];
    const int*   idx     = (const int*)  d_in[2];
    const float* centers = (const float*)d_in[5];
    const float* width   = (const float*)d_in[6];
    const float* W1      = (const float*)d_in[7];
    const float* b1      = (const float*)d_in[8];
    const float* W2      = (const float*)d_in[9];
    const float* b2      = (const float*)d_in[10];
    const float* W3      = (const float*)d_in[11];
    const float* b3      = (const float*)d_in[12];
    const float* scale   = (const float*)d_in[13];
    const float* shift   = (const float*)d_in[14];

    int nAtoms = in_sizes[0] / 3;
    int nEdges = in_sizes[2] / 2;

    size_t m0m1_b = (size_t)nAtoms * 64 * sizeof(float);   // 25.6 MB
    size_t h1_b   = (size_t)nAtoms * HID * 2;              // 102.4 MB
    size_t w1t_b  = (size_t)HID * K1P * 2;                 // 288 KB
    size_t w2t_b  = (size_t)HID * HID * 2;                 // 512 KB
    if (ws_size < m0m1_b + h1_b + w1t_b + w2t_b) return;

    char* ws = (char*)d_ws;
    float* M0M1 = (float*)ws;
    char*  regB = ws + m0m1_b;
    short* h1   = (short*)regB;
    short* W1t  = (short*)(ws + m0m1_b + h1_b);
    short* W2t  = W1t + (size_t)HID * K1P;

    int nb = (nAtoms + 1023) / 1024;
    size_t sorted_b = (size_t)nEdges * sizeof(float4);
    float4* sorted = (float4*)regB;
    int* counts   = (int*)(regB + sorted_b);
    int* starts   = counts + nAtoms;
    int* cursor   = starts + nAtoms + 1;
    int* blockSum = cursor + nAtoms;
    int* blockOff = blockSum + nb;
    if (sorted_b + (size_t)(3 * nAtoms + 1 + 2 * nb) * sizeof(int) > h1_b) return;

    float* out = (float*)d_out;

    hipMemsetAsync(counts, 0, (size_t)nAtoms * sizeof(int), stream);
    hipMemsetAsync(out, 0, sizeof(float), stream);

    convW_kernel<<<dim3(2, K1P), 256, 0, stream>>>(W1, W1t, 272, K1P, HID);
    convW_kernel<<<dim3(2, HID), 256, 0, stream>>>(W2, W2t, HID, HID, HID);

    int eb = (nEdges + 255) / 256;
    hist_kernel <<<eb, 256, 0, stream>>>(idx, counts, nEdges);
    scan1_kernel<<<nb, 1024, 0, stream>>>(counts, starts, blockSum, nAtoms);
    scan2_kernel<<<1, 1024, 0, stream>>>(blockSum, blockOff, starts, nb, nAtoms);
    scan3_kernel<<<nb, 1024, 0, stream>>>(starts, cursor, blockOff, nAtoms);
    scatter_kernel<<<eb, 256, 0, stream>>>(R, idx, cursor, sorted, nEdges);
    accum_kernel<<<(nAtoms + 3) / 4, 256, 0, stream>>>(sorted, starts, centers, width, M0M1, nAtoms);

    int gb = (nAtoms + 127) / 128;
    dim3 g(gb, 2);
    gemm1_mfma<<<g, 512, 0, stream>>>(M0M1, W1t, b1, h1, nAtoms);
    gemm2_mfma<<<g, 512, 0, stream>>>(h1, W2t, b2, W3, b3, scale, shift, Z, out, nAtoms);
}

// Round 8
// 524.047 us; speedup vs baseline: 1.0671x; 1.0671x over previous
//
#include <hip/hip_runtime.h>
#include <hip/hip_bf16.h>
#include <cstdint>

#define HID 512
#define K1P 320   // feat K padded 272 -> 320 (5 x BK64)

typedef __attribute__((ext_vector_type(8))) short bf16x8;
typedef __attribute__((ext_vector_type(4))) float f32x4;

__device__ __forceinline__ short f2bf(float x) {
    __hip_bfloat16 h = __float2bfloat16(x);
    return *(short*)&h;
}
__device__ __forceinline__ float bf2f(short s) {
    unsigned u = ((unsigned)(unsigned short)s) << 16;
    float f; __builtin_memcpy(&f, &u, 4); return f;
}
__device__ __forceinline__ float silu(float x) {
    return x * (1.0f / (1.0f + __expf(-x)));
}
__device__ __forceinline__ void gl_lds16(const void* src, void* dst) {
    __builtin_amdgcn_global_load_lds(
        (const __attribute__((address_space(1))) void*)src,
        (__attribute__((address_space(3))) void*)dst, 16, 0, 0);
}

// ---------- 1) histogram ----------
__global__ __launch_bounds__(256) void hist_kernel(
    const int* __restrict__ idx, int* __restrict__ counts, int nEdges)
{
    int e = blockIdx.x * 256 + threadIdx.x;
    if (e < nEdges) atomicAdd(&counts[idx[e]], 1);
}

// ---------- 2) scan, pass 1 ----------
__global__ __launch_bounds__(1024) void scan1_kernel(
    const int* __restrict__ counts, int* __restrict__ starts,
    int* __restrict__ blockSum, int n)
{
    __shared__ int wsum[16];
    int t = threadIdx.x, lane = t & 63, wid = t >> 6;
    int i = blockIdx.x * 1024 + t;
    int v = (i < n) ? counts[i] : 0;
    int incl = v;
    #pragma unroll
    for (int off = 1; off < 64; off <<= 1) {
        int u = __shfl_up(incl, off);
        if (lane >= off) incl += u;
    }
    if (lane == 63) wsum[wid] = incl;
    __syncthreads();
    if (t < 16) {
        int s = wsum[t];
        #pragma unroll
        for (int off = 1; off < 16; off <<= 1) {
            int u = __shfl_up(s, off);
            if (t >= off) s += u;
        }
        wsum[t] = s;
    }
    __syncthreads();
    int woff = (wid == 0) ? 0 : wsum[wid - 1];
    if (i < n) starts[i] = woff + incl - v;
    if (t == 0) blockSum[blockIdx.x] = wsum[15];
}

// ---------- 2b) scan block sums ----------
__global__ __launch_bounds__(1024) void scan2_kernel(
    const int* __restrict__ blockSum, int* __restrict__ blockOff,
    int* __restrict__ starts, int nb, int n)
{
    __shared__ int arr[1024];
    int t = threadIdx.x;
    int v = (t < nb) ? blockSum[t] : 0;
    arr[t] = v;
    __syncthreads();
    #pragma unroll
    for (int off = 1; off < 1024; off <<= 1) {
        int x = (t >= off) ? arr[t - off] : 0;
        __syncthreads();
        arr[t] += x;
        __syncthreads();
    }
    if (t < nb) blockOff[t] = arr[t] - v;
    if (t == 0) starts[n] = arr[nb - 1];
}

// ---------- 2c) add offsets ----------
__global__ __launch_bounds__(1024) void scan3_kernel(
    int* __restrict__ starts, int* __restrict__ cursor,
    const int* __restrict__ blockOff, int n)
{
    int i = blockIdx.x * 1024 + threadIdx.x;
    if (i < n) {
        int s = starts[i] + blockOff[blockIdx.x];
        starts[i] = s;
        cursor[i] = s;
    }
}

// ---------- 3) scatter ----------
__global__ __launch_bounds__(256) void scatter_kernel(
    const float* __restrict__ R, const int* __restrict__ idx,
    int* __restrict__ cursor, float4* __restrict__ sorted, int nEdges)
{
    int e = blockIdx.x * 256 + threadIdx.x;
    if (e >= nEdges) return;
    int i = idx[e];
    int j = idx[nEdges + e];
    float rix = R[3*(size_t)i], riy = R[3*(size_t)i+1], riz = R[3*(size_t)i+2];
    float rjx = R[3*(size_t)j], rjy = R[3*(size_t)j+1], rjz = R[3*(size_t)j+2];
    float dx = rjx - rix, dy = rjy - riy, dz = rjz - riz;
    float r = sqrtf(dx*dx + dy*dy + dz*dz);
    float inv = 1.0f / (r + 1e-8f);
    int pos = atomicAdd(&cursor[i], 1);
    sorted[pos] = make_float4(r, dx*inv, dy*inv, dz*inv);
}

// ---------- 4) segmented reduce (unroll-4 to batch load latency) ----------
__global__ __launch_bounds__(256) void accum_kernel(
    const float4* __restrict__ sorted, const int* __restrict__ starts,
    const float* __restrict__ centers, const float* __restrict__ width,
    float* __restrict__ M0M1, int nAtoms)
{
    int wv = threadIdx.x >> 6, lane = threadIdx.x & 63;
    int atom = blockIdx.x * 4 + wv;
    if (atom >= nAtoms) return;
    int s = starts[atom], e = starts[atom + 1];
    int k = lane >> 2, c = lane & 3;
    float ck = centers[k];
    float w = width[0];
    float inv2w2 = 1.0f / (2.0f * w * w);
    float acc = 0.0f;
    auto term = [&](float4 v) {
        float diff = v.x - ck;
        float b = __expf(-diff * diff * inv2w2);
        float comp = (c == 0) ? 1.0f : ((c == 1) ? v.y : ((c == 2) ? v.z : v.w));
        return b * comp;
    };
    int p = s;
    for (; p + 3 < e; p += 4) {
        float4 v0 = sorted[p];
        float4 v1 = sorted[p + 1];
        float4 v2 = sorted[p + 2];
        float4 v3 = sorted[p + 3];
        acc += term(v0);
        acc += term(v1);
        acc += term(v2);
        acc += term(v3);
    }
    for (; p < e; ++p) acc += term(sorted[p]);
    M0M1[(size_t)atom * 64 + lane] = acc;
}

// ---------- W -> bf16 transposed ----------
__global__ __launch_bounds__(256) void convW_kernel(
    const float* __restrict__ W, short* __restrict__ Wt, int K, int Kpad, int N)
{
    int n = blockIdx.x * 256 + threadIdx.x;
    int k = blockIdx.y;
    if (n >= N) return;
    float v = (k < K) ? W[(size_t)k * N + n] : 0.0f;
    Wt[(size_t)n * Kpad + k] = f2bf(v);
}

// ---------- GEMM1 MFMA 128x128, BK=64, 2-phase: h1 = silu(feat @ W1 + b1) ----------
__global__ __launch_bounds__(256, 2) void gemm1_mfma(
    const float* __restrict__ M0M1, const short* __restrict__ W1t,
    const float* __restrict__ bias, short* __restrict__ C, int M)
{
    __shared__ short MsT[64][128];         // bf16 transposed M0M1, 16KB
    __shared__ short Asl[2][8 * 128 * 8];  // 2x16KB (ds_write staged)
    __shared__ short Bsl[2][8 * 128 * 8];  // 2x16KB (gl_lds staged)
    int t = threadIdx.x;
    int w = t >> 6, lane = t & 63;
    int wr = w >> 1, wc = w & 1;           // 2x2 wave grid: 64x64 each
    int li = lane & 15, lg = lane >> 4;
    int col0 = blockIdx.x * 128;
    int row0 = blockIdx.y * 128;

    // stage M0M1 transposed into LDS as bf16
    {
        int mrow = t >> 1, mo = (t & 1) * 32;
        int gm = row0 + mrow; if (gm > M - 1) gm = M - 1;
        const float4* src = (const float4*)(M0M1 + (size_t)gm * 64 + mo);
        #pragma unroll
        for (int q = 0; q < 8; ++q) {
            float4 v = src[q];
            int c0 = mo + q * 4;
            MsT[c0+0][mrow] = f2bf(v.x); MsT[c0+1][mrow] = f2bf(v.y);
            MsT[c0+2][mrow] = f2bf(v.z); MsT[c0+3][mrow] = f2bf(v.w);
        }
    }
    __syncthreads();

    auto stageA = [&](int buf, int k0) {   // feat compute -> ds_write, 4 cells/thread
        #pragma unroll
        for (int p = 0; p < 4; ++p) {
            int cell = p * 256 + t;        // 0..1023
            int k8 = cell >> 7, row = cell & 127;
            int kbase = k0 + k8 * 8;
            bf16x8 v;
            if (kbase < 16) {
                #pragma unroll
                for (int j = 0; j < 8; ++j) v[j] = MsT[4*(kbase+j)][row];
            } else if (kbase < 272) {
                int g = kbase - 16, a = g >> 4, b0 = g & 15;
                float ax = bf2f(MsT[4*a+1][row]), ay = bf2f(MsT[4*a+2][row]), az = bf2f(MsT[4*a+3][row]);
                #pragma unroll
                for (int j = 0; j < 8; ++j) {
                    int b = b0 + j;
                    v[j] = f2bf(ax*bf2f(MsT[4*b+1][row]) + ay*bf2f(MsT[4*b+2][row]) + az*bf2f(MsT[4*b+3][row]));
                }
            } else {
                #pragma unroll
                for (int j = 0; j < 8; ++j) v[j] = 0;
            }
            *(bf16x8*)&Asl[buf][cell * 8] = v;
        }
    };
    auto stageB = [&](int buf, int k0) {   // 4 gl_lds per thread
        #pragma unroll
        for (int p = 0; p < 4; ++p) {
            int cell = p * 256 + t;
            int k8 = cell >> 7, n = cell & 127;
            const short* src = W1t + (size_t)(col0 + n) * K1P + k0 + k8 * 8;
            gl_lds16(src, &Bsl[buf][(p * 256 + w * 64) * 8]);
        }
    };

    f32x4 zz = {0.f, 0.f, 0.f, 0.f};
    f32x4 acc[4][4];
    #pragma unroll
    for (int m = 0; m < 4; ++m)
        #pragma unroll
        for (int n = 0; n < 4; ++n) acc[m][n] = zz;

    const int NSTEP = K1P / 64;   // 5
    stageA(0, 0); stageB(0, 0);
    asm volatile("s_waitcnt vmcnt(0) lgkmcnt(0)\n\ts_barrier" ::: "memory");

    for (int s = 0; s < NSTEP; ++s) {
        int cur = s & 1;
        if (s + 1 < NSTEP) { stageB(cur ^ 1, (s + 1) * 64); stageA(cur ^ 1, (s + 1) * 64); }
        #pragma unroll
        for (int ks = 0; ks < 2; ++ks) {
            bf16x8 af[4], bfr[4];
            const short* Ab = &Asl[cur][((ks * 4 + lg) * 128 + wr * 64 + li) * 8];
            const short* Bb = &Bsl[cur][((ks * 4 + lg) * 128 + wc * 64 + li) * 8];
            #pragma unroll
            for (int m = 0; m < 4; ++m) af[m] = *(const bf16x8*)(Ab + m * 128);
            #pragma unroll
            for (int n = 0; n < 4; ++n) bfr[n] = *(const bf16x8*)(Bb + n * 128);
            #pragma unroll
            for (int m = 0; m < 4; ++m)
                #pragma unroll
                for (int n = 0; n < 4; ++n)
                    acc[m][n] = __builtin_amdgcn_mfma_f32_16x16x32_bf16(af[m], bfr[n], acc[m][n], 0, 0, 0);
        }
        asm volatile("s_waitcnt vmcnt(0) lgkmcnt(0)\n\ts_barrier" ::: "memory");
    }

    float bv[4];
    #pragma unroll
    for (int n = 0; n < 4; ++n) bv[n] = bias[col0 + wc * 64 + n * 16 + li];
    #pragma unroll
    for (int m = 0; m < 4; ++m)
        #pragma unroll
        for (int r = 0; r < 4; ++r) {
            int row = row0 + wr * 64 + m * 16 + lg * 4 + r;
            if (row >= M) continue;
            size_t base = (size_t)row * HID + col0 + wc * 64 + li;
            #pragma unroll
            for (int n = 0; n < 4; ++n) {
                float cx = acc[m][n][r] + bv[n];
                C[base + n * 16] = f2bf(silu(cx));
            }
        }
}

// ---------- GEMM2 MFMA 128x128, BK=64, 2-phase + fused energy epilogue ----------
__global__ __launch_bounds__(256, 2) void gemm2_mfma(
    const short* __restrict__ A, const short* __restrict__ W2t,
    const float* __restrict__ bias, const float* __restrict__ W3,
    const float* __restrict__ b3, const float* __restrict__ scale,
    const float* __restrict__ shift, const int* __restrict__ Z,
    float* __restrict__ out, int M)
{
    __shared__ short Asl[2][8 * 128 * 8];  // 2x16KB
    __shared__ short Bsl[2][8 * 128 * 8];  // 2x16KB
    __shared__ float rsum[2][128];
    __shared__ float red[2];
    int t = threadIdx.x;
    int w = t >> 6, lane = t & 63;
    int wr = w >> 1, wc = w & 1;
    int li = lane & 15, lg = lane >> 4;
    int col0 = blockIdx.x * 128;
    int row0 = blockIdx.y * 128;

    auto stage = [&](int buf, int k0) {    // 8 gl_lds per thread
        #pragma unroll
        for (int p = 0; p < 4; ++p) {
            int cell = p * 256 + t;
            int k8 = cell >> 7, row = cell & 127;
            int gr = row0 + row; if (gr > M - 1) gr = M - 1;
            const short* src = A + (size_t)gr * HID + k0 + k8 * 8;
            gl_lds16(src, &Asl[buf][(p * 256 + w * 64) * 8]);
        }
        #pragma unroll
        for (int p = 0; p < 4; ++p) {
            int cell = p * 256 + t;
            int k8 = cell >> 7, n = cell & 127;
            const short* src = W2t + (size_t)(col0 + n) * HID + k0 + k8 * 8;
            gl_lds16(src, &Bsl[buf][(p * 256 + w * 64) * 8]);
        }
    };

    f32x4 zz = {0.f, 0.f, 0.f, 0.f};
    f32x4 acc[4][4];
    #pragma unroll
    for (int m = 0; m < 4; ++m)
        #pragma unroll
        for (int n = 0; n < 4; ++n) acc[m][n] = zz;

    const int NSTEP = HID / 64;   // 8
    stage(0, 0);
    asm volatile("s_waitcnt vmcnt(0)\n\ts_barrier" ::: "memory");

    for (int s = 0; s < NSTEP; ++s) {
        int cur = s & 1;
        if (s + 1 < NSTEP) stage(cur ^ 1, (s + 1) * 64);
        #pragma unroll
        for (int ks = 0; ks < 2; ++ks) {
            bf16x8 af[4], bfr[4];
            const short* Ab = &Asl[cur][((ks * 4 + lg) * 128 + wr * 64 + li) * 8];
            const short* Bb = &Bsl[cur][((ks * 4 + lg) * 128 + wc * 64 + li) * 8];
            #pragma unroll
            for (int m = 0; m < 4; ++m) af[m] = *(const bf16x8*)(Ab + m * 128);
            #pragma unroll
            for (int n = 0; n < 4; ++n) bfr[n] = *(const bf16x8*)(Bb + n * 128);
            #pragma unroll
            for (int m = 0; m < 4; ++m)
                #pragma unroll
                for (int n = 0; n < 4; ++n)
                    acc[m][n] = __builtin_amdgcn_mfma_f32_16x16x32_bf16(af[m], bfr[n], acc[m][n], 0, 0, 0);
        }
        asm volatile("s_waitcnt vmcnt(0) lgkmcnt(0)\n\ts_barrier" ::: "memory");
    }

    float bv[4], w3v[4];
    #pragma unroll
    for (int n = 0; n < 4; ++n) {
        int col = col0 + wc * 64 + n * 16 + li;
        bv[n] = bias[col];
        w3v[n] = W3[col];
    }
    #pragma unroll
    for (int m = 0; m < 4; ++m)
        #pragma unroll
        for (int r = 0; r < 4; ++r) {
            float s = 0.f;
            #pragma unroll
            for (int n = 0; n < 4; ++n) {
                float cx = acc[m][n][r] + bv[n];
                s += silu(cx) * w3v[n];
            }
            #pragma unroll
            for (int off = 1; off < 16; off <<= 1) s += __shfl_xor(s, off);
            if (li == 0) rsum[wc][wr * 64 + m * 16 + lg * 4 + r] = s;
        }
    __syncthreads();
    float e = 0.f;
    if (t < 128) {
        int row = row0 + t;
        if (row < M) {
            float v = rsum[0][t] + rsum[1][t];
            int z = Z[row];
            e = scale[z] * v;
            if (blockIdx.x == 0) e += scale[z] * b3[0] + shift[z];
        }
        #pragma unroll
        for (int off = 32; off > 0; off >>= 1) e += __shfl_down(e, off);
        if ((t & 63) == 0) red[t >> 6] = e;
    }
    __syncthreads();
    if (t == 0) atomicAdd(out, red[0] + red[1]);
}

extern "C" void kernel_launch(void* const* d_in, const int* in_sizes, int n_in,
                              void* d_out, int out_size, void* d_ws, size_t ws_size,
                              hipStream_t stream)
{
    const float* R       = (const float*)d_in[0];
    const int*   Z       = (const int*)  d_in[1];
    const int*   idx     = (const int*)  d_in[2];
    const float* centers = (const float*)d_in[5];
    const float* width   = (const float*)d_in[6];
    const float* W1      = (const float*)d_in[7];
    const float* b1      = (const float*)d_in[8];
    const float* W2      = (const float*)d_in[9];
    const float* b2      = (const float*)d_in[10];
    const float* W3      = (const float*)d_in[11];
    const float* b3      = (const float*)d_in[12];
    const float* scale   = (const float*)d_in[13];
    const float* shift   = (const float*)d_in[14];

    int nAtoms = in_sizes[0] / 3;
    int nEdges = in_sizes[2] / 2;

    size_t m0m1_b = (size_t)nAtoms * 64 * sizeof(float);   // 25.6 MB
    size_t h1_b   = (size_t)nAtoms * HID * 2;              // 102.4 MB
    size_t w1t_b  = (size_t)HID * K1P * 2;                 // 320 KB
    size_t w2t_b  = (size_t)HID * HID * 2;                 // 512 KB
    if (ws_size < m0m1_b + h1_b + w1t_b + w2t_b) return;

    char* ws = (char*)d_ws;
    float* M0M1 = (float*)ws;
    char*  regB = ws + m0m1_b;
    short* h1   = (short*)regB;
    short* W1t  = (short*)(ws + m0m1_b + h1_b);
    short* W2t  = W1t + (size_t)HID * K1P;

    int nb = (nAtoms + 1023) / 1024;
    size_t sorted_b = (size_t)nEdges * sizeof(float4);
    float4* sorted = (float4*)regB;
    int* counts   = (int*)(regB + sorted_b);
    int* starts   = counts + nAtoms;
    int* cursor   = starts + nAtoms + 1;
    int* blockSum = cursor + nAtoms;
    int* blockOff = blockSum + nb;
    if (sorted_b + (size_t)(3 * nAtoms + 1 + 2 * nb) * sizeof(int) > h1_b) return;

    float* out = (float*)d_out;

    hipMemsetAsync(counts, 0, (size_t)nAtoms * sizeof(int), stream);
    hipMemsetAsync(out, 0, sizeof(float), stream);

    convW_kernel<<<dim3(2, K1P), 256, 0, stream>>>(W1, W1t, 272, K1P, HID);
    convW_kernel<<<dim3(2, HID), 256, 0, stream>>>(W2, W2t, HID, HID, HID);

    int eb = (nEdges + 255) / 256;
    hist_kernel <<<eb, 256, 0, stream>>>(idx, counts, nEdges);
    scan1_kernel<<<nb, 1024, 0, stream>>>(counts, starts, blockSum, nAtoms);
    scan2_kernel<<<1, 1024, 0, stream>>>(blockSum, blockOff, starts, nb, nAtoms);
    scan3_kernel<<<nb, 1024, 0, stream>>>(starts, cursor, blockOff, nAtoms);
    scatter_kernel<<<eb, 256, 0, stream>>>(R, idx, cursor, sorted, nEdges);
    accum_kernel<<<(nAtoms + 3) / 4, 256, 0, stream>>>(sorted, starts, centers, width, M0M1, nAtoms);

    int gb = (nAtoms + 127) / 128;
    dim3 g(4, gb);   // col-fast: sibling col-blocks adjacent -> A reused in L2/LLC
    gemm1_mfma<<<g, 256, 0, stream>>>(M0M1, W1t, b1, h1, nAtoms);
    gemm2_mfma<<<g, 256, 0, stream>>>(h1, W2t, b2, W3, b3, scale, shift, Z, out, nAtoms);
}

// Round 9
// 506.987 us; speedup vs baseline: 1.1030x; 1.0336x over previous
//
#include <hip/hip_runtime.h>
#include <hip/hip_bf16.h>
#include <cstdint>

#define HID 512
#define K1P 320   // feat K padded 272 -> 320 (5 x BK64)

typedef __attribute__((ext_vector_type(8))) short bf16x8;
typedef __attribute__((ext_vector_type(4))) float f32x4;

__device__ __forceinline__ short f2bf(float x) {
    __hip_bfloat16 h = __float2bfloat16(x);
    return *(short*)&h;
}
__device__ __forceinline__ float bfbits2f(unsigned bits) {
    float f; __builtin_memcpy(&f, &bits, 4); return f;
}
__device__ __forceinline__ float silu(float x) {
    return x * (1.0f / (1.0f + __expf(-x)));
}
__device__ __forceinline__ void gl_lds16(const void* src, void* dst) {
    __builtin_amdgcn_global_load_lds(
        (const __attribute__((address_space(1))) void*)src,
        (__attribute__((address_space(3))) void*)dst, 16, 0, 0);
}

// ---------- 1) histogram ----------
__global__ __launch_bounds__(256) void hist_kernel(
    const int* __restrict__ idx, int* __restrict__ counts, int nEdges)
{
    int e = blockIdx.x * 256 + threadIdx.x;
    if (e < nEdges) atomicAdd(&counts[idx[e]], 1);
}

// ---------- 2) scan, pass 1 ----------
__global__ __launch_bounds__(1024) void scan1_kernel(
    const int* __restrict__ counts, int* __restrict__ starts,
    int* __restrict__ blockSum, int n)
{
    __shared__ int wsum[16];
    int t = threadIdx.x, lane = t & 63, wid = t >> 6;
    int i = blockIdx.x * 1024 + t;
    int v = (i < n) ? counts[i] : 0;
    int incl = v;
    #pragma unroll
    for (int off = 1; off < 64; off <<= 1) {
        int u = __shfl_up(incl, off);
        if (lane >= off) incl += u;
    }
    if (lane == 63) wsum[wid] = incl;
    __syncthreads();
    if (t < 16) {
        int s = wsum[t];
        #pragma unroll
        for (int off = 1; off < 16; off <<= 1) {
            int u = __shfl_up(s, off);
            if (t >= off) s += u;
        }
        wsum[t] = s;
    }
    __syncthreads();
    int woff = (wid == 0) ? 0 : wsum[wid - 1];
    if (i < n) starts[i] = woff + incl - v;
    if (t == 0) blockSum[blockIdx.x] = wsum[15];
}

// ---------- 2b) scan block sums ----------
__global__ __launch_bounds__(1024) void scan2_kernel(
    const int* __restrict__ blockSum, int* __restrict__ blockOff,
    int* __restrict__ starts, int nb, int n)
{
    __shared__ int arr[1024];
    int t = threadIdx.x;
    int v = (t < nb) ? blockSum[t] : 0;
    arr[t] = v;
    __syncthreads();
    #pragma unroll
    for (int off = 1; off < 1024; off <<= 1) {
        int x = (t >= off) ? arr[t - off] : 0;
        __syncthreads();
        arr[t] += x;
        __syncthreads();
    }
    if (t < nb) blockOff[t] = arr[t] - v;
    if (t == 0) starts[n] = arr[nb - 1];
}

// ---------- 2c) add offsets ----------
__global__ __launch_bounds__(1024) void scan3_kernel(
    int* __restrict__ starts, int* __restrict__ cursor,
    const int* __restrict__ blockOff, int n)
{
    int i = blockIdx.x * 1024 + threadIdx.x;
    if (i < n) {
        int s = starts[i] + blockOff[blockIdx.x];
        starts[i] = s;
        cursor[i] = s;
    }
}

// ---------- 3) scatter ----------
__global__ __launch_bounds__(256) void scatter_kernel(
    const float* __restrict__ R, const int* __restrict__ idx,
    int* __restrict__ cursor, float4* __restrict__ sorted, int nEdges)
{
    int e = blockIdx.x * 256 + threadIdx.x;
    if (e >= nEdges) return;
    int i = idx[e];
    int j = idx[nEdges + e];
    float rix = R[3*(size_t)i], riy = R[3*(size_t)i+1], riz = R[3*(size_t)i+2];
    float rjx = R[3*(size_t)j], rjy = R[3*(size_t)j+1], rjz = R[3*(size_t)j+2];
    float dx = rjx - rix, dy = rjy - riy, dz = rjz - riz;
    float r = sqrtf(dx*dx + dy*dy + dz*dz);
    float inv = 1.0f / (r + 1e-8f);
    int pos = atomicAdd(&cursor[i], 1);
    sorted[pos] = make_float4(r, dx*inv, dy*inv, dz*inv);
}

// ---------- 4) segmented reduce (unroll-4) ----------
__global__ __launch_bounds__(256) void accum_kernel(
    const float4* __restrict__ sorted, const int* __restrict__ starts,
    const float* __restrict__ centers, const float* __restrict__ width,
    float* __restrict__ M0M1, int nAtoms)
{
    int wv = threadIdx.x >> 6, lane = threadIdx.x & 63;
    int atom = blockIdx.x * 4 + wv;
    if (atom >= nAtoms) return;
    int s = starts[atom], e = starts[atom + 1];
    int k = lane >> 2, c = lane & 3;
    float ck = centers[k];
    float w = width[0];
    float inv2w2 = 1.0f / (2.0f * w * w);
    float acc = 0.0f;
    auto term = [&](float4 v) {
        float diff = v.x - ck;
        float b = __expf(-diff * diff * inv2w2);
        float comp = (c == 0) ? 1.0f : ((c == 1) ? v.y : ((c == 2) ? v.z : v.w));
        return b * comp;
    };
    int p = s;
    for (; p + 3 < e; p += 4) {
        float4 v0 = sorted[p];
        float4 v1 = sorted[p + 1];
        float4 v2 = sorted[p + 2];
        float4 v3 = sorted[p + 3];
        acc += term(v0); acc += term(v1); acc += term(v2); acc += term(v3);
    }
    for (; p < e; ++p) acc += term(sorted[p]);
    M0M1[(size_t)atom * 64 + lane] = acc;
}

// ---------- W -> bf16 transposed ----------
__global__ __launch_bounds__(256) void convW_kernel(
    const float* __restrict__ W, short* __restrict__ Wt, int K, int Kpad, int N)
{
    int n = blockIdx.x * 256 + threadIdx.x;
    int k = blockIdx.y;
    if (n >= N) return;
    float v = (k < K) ? W[(size_t)k * N + n] : 0.0f;
    Wt[(size_t)n * Kpad + k] = f2bf(v);
}

// ============ GEMM1: 256x256 tile, 8-wave, K-half phases, reg-feat A ============
__global__ __launch_bounds__(512, 2) void gemm1_mfma(
    const float* __restrict__ M0M1, const short* __restrict__ W1t,
    const float* __restrict__ bias, short* __restrict__ C, int M)
{
    __shared__ short Asl[2][2][8192];   // [half][buf][(k8*256+row)*8]
    __shared__ short Bsl[2][2][8192];
    int t = threadIdx.x;
    int w = t >> 6, lane = t & 63;
    int wr = w >> 2, wc = w & 3;        // 2x4 waves, each 128 rows x 64 cols
    int li = lane & 15, lg = lane >> 4;
    int row0 = blockIdx.y * 256;
    int col0 = blockIdx.x * 256;

    // per-thread M0M1 row in packed bf16 registers (2 threads share a row)
    int myrow = t >> 1, hh = t & 1;
    int gm = row0 + myrow; if (gm > M - 1) gm = M - 1;
    const float4* mr = (const float4*)(M0M1 + (size_t)gm * 64);
    unsigned pk[32];
    #pragma unroll
    for (int q = 0; q < 16; ++q) {
        float4 v = mr[q];
        pk[2*q]   = ((unsigned)(unsigned short)f2bf(v.x)) | (((unsigned)(unsigned short)f2bf(v.y)) << 16);
        pk[2*q+1] = ((unsigned)(unsigned short)f2bf(v.z)) | (((unsigned)(unsigned short)f2bf(v.w)) << 16);
    }
    auto getbits = [&](int i) -> short {
        unsigned u = pk[i >> 1];
        return (short)((i & 1) ? (u >> 16) : (u & 0xffffu));
    };
    auto getf = [&](int i) -> float {
        unsigned u = pk[i >> 1];
        unsigned b = (i & 1) ? (u & 0xffff0000u) : (u << 16);
        return bfbits2f(b);
    };
    // compute one 8-feature cell (kbase..kbase+7) for my row, write to Asl[H][b]
    auto doCell = [&](int kt, int H, int b, int k8w) {
        int kbase = kt * 64 + k8w * 8;
        bf16x8 v;
        if (kbase < 16) {
            #pragma unroll
            for (int j = 0; j < 8; ++j) v[j] = getbits(4 * (kbase + j));
        } else if (kbase < 272) {
            int g = kbase - 16, a = g >> 4, b0 = g & 15;
            float ax = getf(4*a+1), ay = getf(4*a+2), az = getf(4*a+3);
            #pragma unroll
            for (int j = 0; j < 8; ++j) {
                int bb = b0 + j;
                float f = ax*getf(4*bb+1) + ay*getf(4*bb+2) + az*getf(4*bb+3);
                v[j] = f2bf(f);
            }
        } else {
            #pragma unroll
            for (int j = 0; j < 8; ++j) v[j] = 0;
        }
        *(bf16x8*)&Asl[H][b][((k8w & 3) * 256 + myrow) * 8] = v;
    };
    auto stageA = [&](int kt, int H, int b) {
        if (hh == 0) { doCell(kt, H, b, H*4 + 0); doCell(kt, H, b, H*4 + 1); }
        else         { doCell(kt, H, b, H*4 + 2); doCell(kt, H, b, H*4 + 3); }
    };
    auto stageB = [&](int kt, int H, int b) {    // 2 gl_lds per thread
        #pragma unroll
        for (int p = 0; p < 2; ++p) {
            int cell = p * 512 + t;
            int k8 = cell >> 8, col = cell & 255;
            const short* src = W1t + (size_t)(col0 + col) * K1P + kt*64 + H*32 + k8*8;
            gl_lds16(src, &Bsl[H][b][(p * 512 + w * 64) * 8]);
        }
    };

    f32x4 acc[8][4] = {};

    // prologue: tile 0 fully staged
    stageA(0, 0, 0); stageA(0, 1, 0);
    stageB(0, 0, 0); stageB(0, 1, 0);

    #pragma unroll
    for (int tt = 0; tt < 5; ++tt) {
        int b = tt & 1, nb = b ^ 1;
        // phase 1 (k-half 0): B(tt)H0 complete, B(tt)H1 may remain in flight
        asm volatile("s_waitcnt vmcnt(2) lgkmcnt(0)\n\ts_barrier" ::: "memory");
        if (tt + 1 < 5) stageB(tt + 1, 0, nb);
        {
            bf16x8 af[8], bfr[4];
            #pragma unroll
            for (int m = 0; m < 8; ++m)
                af[m] = *(const bf16x8*)&Asl[0][b][(lg*256 + wr*128 + m*16 + li) * 8];
            #pragma unroll
            for (int n = 0; n < 4; ++n)
                bfr[n] = *(const bf16x8*)&Bsl[0][b][(lg*256 + wc*64 + n*16 + li) * 8];
            if (tt + 1 < 5) stageA(tt + 1, 0, nb);
            __builtin_amdgcn_s_setprio(1);
            #pragma unroll
            for (int m = 0; m < 8; ++m)
                #pragma unroll
                for (int n = 0; n < 4; ++n)
                    acc[m][n] = __builtin_amdgcn_mfma_f32_16x16x32_bf16(af[m], bfr[n], acc[m][n], 0, 0, 0);
            __builtin_amdgcn_s_setprio(0);
        }
        // phase 2 (k-half 1)
        if (tt < 4) asm volatile("s_waitcnt vmcnt(2) lgkmcnt(0)\n\ts_barrier" ::: "memory");
        else        asm volatile("s_waitcnt vmcnt(0) lgkmcnt(0)\n\ts_barrier" ::: "memory");
        if (tt + 1 < 5) stageB(tt + 1, 1, nb);
        {
            bf16x8 af[8], bfr[4];
            #pragma unroll
            for (int m = 0; m < 8; ++m)
                af[m] = *(const bf16x8*)&Asl[1][b][(lg*256 + wr*128 + m*16 + li) * 8];
            #pragma unroll
            for (int n = 0; n < 4; ++n)
                bfr[n] = *(const bf16x8*)&Bsl[1][b][(lg*256 + wc*64 + n*16 + li) * 8];
            if (tt + 1 < 5) stageA(tt + 1, 1, nb);
            __builtin_amdgcn_s_setprio(1);
            #pragma unroll
            for (int m = 0; m < 8; ++m)
                #pragma unroll
                for (int n = 0; n < 4; ++n)
                    acc[m][n] = __builtin_amdgcn_mfma_f32_16x16x32_bf16(af[m], bfr[n], acc[m][n], 0, 0, 0);
            __builtin_amdgcn_s_setprio(0);
        }
    }

    float bv[4];
    #pragma unroll
    for (int n = 0; n < 4; ++n) bv[n] = bias[col0 + wc*64 + n*16 + li];
    #pragma unroll
    for (int m = 0; m < 8; ++m)
        #pragma unroll
        for (int r = 0; r < 4; ++r) {
            int row = row0 + wr*128 + m*16 + lg*4 + r;
            if (row >= M) continue;
            size_t base = (size_t)row * HID + col0 + wc*64 + li;
            #pragma unroll
            for (int n = 0; n < 4; ++n) {
                float cx = acc[m][n][r] + bv[n];
                C[base + n*16] = f2bf(silu(cx));
            }
        }
}

// ============ GEMM2: 256x256 tile, 8-wave, K-half phases + fused energy ============
__global__ __launch_bounds__(512, 2) void gemm2_mfma(
    const short* __restrict__ A, const short* __restrict__ W2t,
    const float* __restrict__ bias, const float* __restrict__ W3,
    const float* __restrict__ b3, const float* __restrict__ scale,
    const float* __restrict__ shift, const int* __restrict__ Z,
    float* __restrict__ out, int M)
{
    __shared__ short Asl[2][2][8192];   // [half][buf]
    __shared__ short Bsl[2][2][8192];
    int t = threadIdx.x;
    int w = t >> 6, lane = t & 63;
    int wr = w >> 2, wc = w & 3;
    int li = lane & 15, lg = lane >> 4;
    int row0 = blockIdx.y * 256;
    int col0 = blockIdx.x * 256;

    auto stage = [&](int kt, int H, int b) {   // A 2 + B 2 gl_lds per thread
        #pragma unroll
        for (int p = 0; p < 2; ++p) {
            int cell = p * 512 + t;
            int k8 = cell >> 8, row = cell & 255;
            int gr = row0 + row; if (gr > M - 1) gr = M - 1;
            const short* src = A + (size_t)gr * HID + kt*64 + H*32 + k8*8;
            gl_lds16(src, &Asl[H][b][(p * 512 + w * 64) * 8]);
        }
        #pragma unroll
        for (int p = 0; p < 2; ++p) {
            int cell = p * 512 + t;
            int k8 = cell >> 8, col = cell & 255;
            const short* src = W2t + (size_t)(col0 + col) * HID + kt*64 + H*32 + k8*8;
            gl_lds16(src, &Bsl[H][b][(p * 512 + w * 64) * 8]);
        }
    };

    f32x4 acc[8][4] = {};

    stage(0, 0, 0); stage(0, 1, 0);   // 8 loads in flight

    for (int tt = 0; tt < 8; ++tt) {
        int b = tt & 1, nb = b ^ 1;
        asm volatile("s_waitcnt vmcnt(4)\n\ts_barrier" ::: "memory");
        if (tt + 1 < 8) stage(tt + 1, 0, nb);
        {
            bf16x8 af[8], bfr[4];
            #pragma unroll
            for (int m = 0; m < 8; ++m)
                af[m] = *(const bf16x8*)&Asl[0][b][(lg*256 + wr*128 + m*16 + li) * 8];
            #pragma unroll
            for (int n = 0; n < 4; ++n)
                bfr[n] = *(const bf16x8*)&Bsl[0][b][(lg*256 + wc*64 + n*16 + li) * 8];
            __builtin_amdgcn_s_setprio(1);
            #pragma unroll
            for (int m = 0; m < 8; ++m)
                #pragma unroll
                for (int n = 0; n < 4; ++n)
                    acc[m][n] = __builtin_amdgcn_mfma_f32_16x16x32_bf16(af[m], bfr[n], acc[m][n], 0, 0, 0);
            __builtin_amdgcn_s_setprio(0);
        }
        if (tt < 7) asm volatile("s_waitcnt vmcnt(4)\n\ts_barrier" ::: "memory");
        else        asm volatile("s_waitcnt vmcnt(0)\n\ts_barrier" ::: "memory");
        if (tt + 1 < 8) stage(tt + 1, 1, nb);
        {
            bf16x8 af[8], bfr[4];
            #pragma unroll
            for (int m = 0; m < 8; ++m)
                af[m] = *(const bf16x8*)&Asl[1][b][(lg*256 + wr*128 + m*16 + li) * 8];
            #pragma unroll
            for (int n = 0; n < 4; ++n)
                bfr[n] = *(const bf16x8*)&Bsl[1][b][(lg*256 + wc*64 + n*16 + li) * 8];
            __builtin_amdgcn_s_setprio(1);
            #pragma unroll
            for (int m = 0; m < 8; ++m)
                #pragma unroll
                for (int n = 0; n < 4; ++n)
                    acc[m][n] = __builtin_amdgcn_mfma_f32_16x16x32_bf16(af[m], bfr[n], acc[m][n], 0, 0, 0);
            __builtin_amdgcn_s_setprio(0);
        }
    }

    // ---- fused epilogue: silu + W3 dot + scale/shift + block energy sum ----
    // rsum aliased into Asl[0][0] (dead: final phases only touch [*][1])
    float* rsum = (float*)&Asl[0][0][0];    // [4][256]
    float* red  = rsum + 1024;              // 8 floats
    float bv[4], w3v[4];
    #pragma unroll
    for (int n = 0; n < 4; ++n) {
        int col = col0 + wc*64 + n*16 + li;
        bv[n]  = bias[col];
        w3v[n] = W3[col];
    }
    #pragma unroll
    for (int m = 0; m < 8; ++m)
        #pragma unroll
        for (int r = 0; r < 4; ++r) {
            float s = 0.f;
            #pragma unroll
            for (int n = 0; n < 4; ++n) {
                float cx = acc[m][n][r] + bv[n];
                s += silu(cx) * w3v[n];
            }
            #pragma unroll
            for (int off = 1; off < 16; off <<= 1) s += __shfl_xor(s, off);
            if (li == 0) rsum[wc * 256 + wr*128 + m*16 + lg*4 + r] = s;
        }
    __syncthreads();
    float e = 0.f;
    if (t < 256) {
        int row = row0 + t;
        if (row < M) {
            float v = rsum[t] + rsum[256 + t] + rsum[512 + t] + rsum[768 + t];
            int z = Z[row];
            e = scale[z] * v;
            if (blockIdx.x == 0) e += scale[z] * b3[0] + shift[z];
        }
    }
    #pragma unroll
    for (int off = 32; off > 0; off >>= 1) e += __shfl_down(e, off);
    if (lane == 0) red[w] = e;
    __syncthreads();
    if (t == 0) {
        float s = red[0] + red[1] + red[2] + red[3] + red[4] + red[5] + red[6] + red[7];
        atomicAdd(out, s);
    }
}

extern "C" void kernel_launch(void* const* d_in, const int* in_sizes, int n_in,
                              void* d_out, int out_size, void* d_ws, size_t ws_size,
                              hipStream_t stream)
{
    const float* R       = (const float*)d_in[0];
    const int*   Z       = (const int*)  d_in[1];
    const int*   idx     = (const int*)  d_in[2];
    const float* centers = (const float*)d_in[5];
    const float* width   = (const float*)d_in[6];
    const float* W1      = (const float*)d_in[7];
    const float* b1      = (const float*)d_in[8];
    const float* W2      = (const float*)d_in[9];
    const float* b2      = (const float*)d_in[10];
    const float* W3      = (const float*)d_in[11];
    const float* b3      = (const float*)d_in[12];
    const float* scale   = (const float*)d_in[13];
    const float* shift   = (const float*)d_in[14];

    int nAtoms = in_sizes[0] / 3;
    int nEdges = in_sizes[2] / 2;

    size_t m0m1_b = (size_t)nAtoms * 64 * sizeof(float);   // 25.6 MB
    size_t h1_b   = (size_t)nAtoms * HID * 2;              // 102.4 MB
    size_t w1t_b  = (size_t)HID * K1P * 2;                 // 320 KB
    size_t w2t_b  = (size_t)HID * HID * 2;                 // 512 KB
    if (ws_size < m0m1_b + h1_b + w1t_b + w2t_b) return;

    char* ws = (char*)d_ws;
    float* M0M1 = (float*)ws;
    char*  regB = ws + m0m1_b;
    short* h1   = (short*)regB;
    short* W1t  = (short*)(ws + m0m1_b + h1_b);
    short* W2t  = W1t + (size_t)HID * K1P;

    int nb = (nAtoms + 1023) / 1024;
    size_t sorted_b = (size_t)nEdges * sizeof(float4);
    float4* sorted = (float4*)regB;
    int* counts   = (int*)(regB + sorted_b);
    int* starts   = counts + nAtoms;
    int* cursor   = starts + nAtoms + 1;
    int* blockSum = cursor + nAtoms;
    int* blockOff = blockSum + nb;
    if (sorted_b + (size_t)(3 * nAtoms + 1 + 2 * nb) * sizeof(int) > h1_b) return;

    float* out = (float*)d_out;

    hipMemsetAsync(counts, 0, (size_t)nAtoms * sizeof(int), stream);
    hipMemsetAsync(out, 0, sizeof(float), stream);

    convW_kernel<<<dim3(2, K1P), 256, 0, stream>>>(W1, W1t, 272, K1P, HID);
    convW_kernel<<<dim3(2, HID), 256, 0, stream>>>(W2, W2t, HID, HID, HID);

    int eb = (nEdges + 255) / 256;
    hist_kernel <<<eb, 256, 0, stream>>>(idx, counts, nEdges);
    scan1_kernel<<<nb, 1024, 0, stream>>>(counts, starts, blockSum, nAtoms);
    scan2_kernel<<<1, 1024, 0, stream>>>(blockSum, blockOff, starts, nb, nAtoms);
    scan3_kernel<<<nb, 1024, 0, stream>>>(starts, cursor, blockOff, nAtoms);
    scatter_kernel<<<eb, 256, 0, stream>>>(R, idx, cursor, sorted, nEdges);
    accum_kernel<<<(nAtoms + 3) / 4, 256, 0, stream>>>(sorted, starts, centers, width, M0M1, nAtoms);

    int gb = (nAtoms + 255) / 256;
    dim3 g(2, gb);   // col-fast: sibling col-blocks adjacent -> A reused in L2/LLC
    gemm1_mfma<<<g, 512, 0, stream>>>(M0M1, W1t, b1, h1, nAtoms);
    gemm2_mfma<<<g, 512, 0, stream>>>(h1, W2t, b2, W3, b3, scale, shift, Z, out, nAtoms);
}

// Round 10
// 476.007 us; speedup vs baseline: 1.1748x; 1.0651x over previous
//
#include <hip/hip_runtime.h>
#include <hip/hip_bf16.h>
#include <cstdint>

#define HID 512
#define K1P 288   // feat K padded 272 -> 288 (9 x BK32)

typedef __attribute__((ext_vector_type(8))) short bf16x8;
typedef __attribute__((ext_vector_type(4))) float f32x4;

__device__ __forceinline__ short f2bf(float x) {
    __hip_bfloat16 h = __float2bfloat16(x);
    return *(short*)&h;
}
__device__ __forceinline__ float silu(float x) {
    return x * (1.0f / (1.0f + __expf(-x)));
}
__device__ __forceinline__ void gl_lds16(const void* src, void* dst) {
    __builtin_amdgcn_global_load_lds(
        (const __attribute__((address_space(1))) void*)src,
        (__attribute__((address_space(3))) void*)dst, 16, 0, 0);
}
// bijective XCD swizzle (m204): consecutive 1/8-chunks of the grid per XCD
__device__ __forceinline__ int xcd_swz(int bid, int nwg) {
    int q = nwg >> 3, r = nwg & 7;
    int xcd = bid & 7, i = bid >> 3;
    int base = (xcd < r) ? xcd * (q + 1) : r * (q + 1) + (xcd - r) * q;
    return base + i;
}

// ---------- 1) histogram ----------
__global__ __launch_bounds__(256) void hist_kernel(
    const int* __restrict__ idx, int* __restrict__ counts, int nEdges)
{
    int e = blockIdx.x * 256 + threadIdx.x;
    if (e < nEdges) atomicAdd(&counts[idx[e]], 1);
}

// ---------- 2) scan, pass 1 ----------
__global__ __launch_bounds__(1024) void scan1_kernel(
    const int* __restrict__ counts, int* __restrict__ starts,
    int* __restrict__ blockSum, int n)
{
    __shared__ int wsum[16];
    int t = threadIdx.x, lane = t & 63, wid = t >> 6;
    int i = blockIdx.x * 1024 + t;
    int v = (i < n) ? counts[i] : 0;
    int incl = v;
    #pragma unroll
    for (int off = 1; off < 64; off <<= 1) {
        int u = __shfl_up(incl, off);
        if (lane >= off) incl += u;
    }
    if (lane == 63) wsum[wid] = incl;
    __syncthreads();
    if (t < 16) {
        int s = wsum[t];
        #pragma unroll
        for (int off = 1; off < 16; off <<= 1) {
            int u = __shfl_up(s, off);
            if (t >= off) s += u;
        }
        wsum[t] = s;
    }
    __syncthreads();
    int woff = (wid == 0) ? 0 : wsum[wid - 1];
    if (i < n) starts[i] = woff + incl - v;
    if (t == 0) blockSum[blockIdx.x] = wsum[15];
}

// ---------- 2b) scan block sums ----------
__global__ __launch_bounds__(1024) void scan2_kernel(
    const int* __restrict__ blockSum, int* __restrict__ blockOff,
    int* __restrict__ starts, int nb, int n)
{
    __shared__ int arr[1024];
    int t = threadIdx.x;
    int v = (t < nb) ? blockSum[t] : 0;
    arr[t] = v;
    __syncthreads();
    #pragma unroll
    for (int off = 1; off < 1024; off <<= 1) {
        int x = (t >= off) ? arr[t - off] : 0;
        __syncthreads();
        arr[t] += x;
        __syncthreads();
    }
    if (t < nb) blockOff[t] = arr[t] - v;
    if (t == 0) starts[n] = arr[nb - 1];
}

// ---------- 2c) add offsets ----------
__global__ __launch_bounds__(1024) void scan3_kernel(
    int* __restrict__ starts, int* __restrict__ cursor,
    const int* __restrict__ blockOff, int n)
{
    int i = blockIdx.x * 1024 + threadIdx.x;
    if (i < n) {
        int s = starts[i] + blockOff[blockIdx.x];
        starts[i] = s;
        cursor[i] = s;
    }
}

// ---------- 3) scatter ----------
__global__ __launch_bounds__(256) void scatter_kernel(
    const float* __restrict__ R, const int* __restrict__ idx,
    int* __restrict__ cursor, float4* __restrict__ sorted, int nEdges)
{
    int e = blockIdx.x * 256 + threadIdx.x;
    if (e >= nEdges) return;
    int i = idx[e];
    int j = idx[nEdges + e];
    float rix = R[3*(size_t)i], riy = R[3*(size_t)i+1], riz = R[3*(size_t)i+2];
    float rjx = R[3*(size_t)j], rjy = R[3*(size_t)j+1], rjz = R[3*(size_t)j+2];
    float dx = rjx - rix, dy = rjy - riy, dz = rjz - riz;
    float r = sqrtf(dx*dx + dy*dy + dz*dz);
    float inv = 1.0f / (r + 1e-8f);
    int pos = atomicAdd(&cursor[i], 1);
    sorted[pos] = make_float4(r, dx*inv, dy*inv, dz*inv);
}

// ---------- 4) segmented reduce (unroll-4) ----------
__global__ __launch_bounds__(256) void accum_kernel(
    const float4* __restrict__ sorted, const int* __restrict__ starts,
    const float* __restrict__ centers, const float* __restrict__ width,
    float* __restrict__ M0M1, int nAtoms)
{
    int wv = threadIdx.x >> 6, lane = threadIdx.x & 63;
    int atom = blockIdx.x * 4 + wv;
    if (atom >= nAtoms) return;
    int s = starts[atom], e = starts[atom + 1];
    int k = lane >> 2, c = lane & 3;
    float ck = centers[k];
    float w = width[0];
    float inv2w2 = 1.0f / (2.0f * w * w);
    float acc = 0.0f;
    auto term = [&](float4 v) {
        float diff = v.x - ck;
        float b = __expf(-diff * diff * inv2w2);
        float comp = (c == 0) ? 1.0f : ((c == 1) ? v.y : ((c == 2) ? v.z : v.w));
        return b * comp;
    };
    int p = s;
    for (; p + 3 < e; p += 4) {
        float4 v0 = sorted[p];
        float4 v1 = sorted[p + 1];
        float4 v2 = sorted[p + 2];
        float4 v3 = sorted[p + 3];
        acc += term(v0); acc += term(v1); acc += term(v2); acc += term(v3);
    }
    for (; p < e; ++p) acc += term(sorted[p]);
    M0M1[(size_t)atom * 64 + lane] = acc;
}

// ---------- W -> bf16 transposed ----------
__global__ __launch_bounds__(256) void convW_kernel(
    const float* __restrict__ W, short* __restrict__ Wt, int K, int Kpad, int N)
{
    int n = blockIdx.x * 256 + threadIdx.x;
    int k = blockIdx.y;
    if (n >= N) return;
    float v = (k < K) ? W[(size_t)k * N + n] : 0.0f;
    Wt[(size_t)n * Kpad + k] = f2bf(v);
}

// ============ GEMM1: 128x128, BK=32, 4-buf deep pipeline, feat A from MsT ============
__global__ __launch_bounds__(256, 2) void gemm1_mfma(
    const float* __restrict__ M0M1, const short* __restrict__ W1t,
    const float* __restrict__ bias, short* __restrict__ C, int M, int nwg)
{
    __shared__ float MsT[64][128];     // 32KB: transposed M0M1 [comp][row]
    __shared__ short Asl[2][4096];     // 2x8KB (ds_write staged feat)
    __shared__ short Bsl[4][4096];     // 4x8KB (gl_lds staged, 3-ahead)
    int t = threadIdx.x;
    int w = t >> 6, lane = t & 63;
    int wr = w >> 1, wc = w & 1;       // 2x2 wave grid: 64x64 each
    int li = lane & 15, lg = lane >> 4;
    int lin = xcd_swz(blockIdx.x, nwg);
    int row0 = (lin >> 2) * 128;
    int col0 = (lin & 3) * 128;

    // stage M0M1 transposed (f32) into LDS
    {
        int mrow = t >> 1, mo = (t & 1) * 32;
        int gm = row0 + mrow; if (gm > M - 1) gm = M - 1;
        const float4* src = (const float4*)(M0M1 + (size_t)gm * 64 + mo);
        #pragma unroll
        for (int q = 0; q < 8; ++q) {
            float4 v = src[q];
            int c0 = mo + q * 4;
            MsT[c0+0][mrow] = v.x; MsT[c0+1][mrow] = v.y;
            MsT[c0+2][mrow] = v.z; MsT[c0+3][mrow] = v.w;
        }
    }
    __syncthreads();

    auto stageA = [&](int kt, int buf) {   // 2 cells/thread, feat -> ds_write
        #pragma unroll
        for (int p = 0; p < 2; ++p) {
            int cell = p * 256 + t;        // 0..511
            int k8 = cell >> 7, row = cell & 127;
            int kbase = kt * 32 + k8 * 8;
            bf16x8 v;
            if (kbase < 16) {
                #pragma unroll
                for (int j = 0; j < 8; ++j) v[j] = f2bf(MsT[4*(kbase+j)][row]);
            } else if (kbase < 272) {
                int g = kbase - 16, a = g >> 4, b0 = g & 15;
                float ax = MsT[4*a+1][row], ay = MsT[4*a+2][row], az = MsT[4*a+3][row];
                #pragma unroll
                for (int j = 0; j < 8; ++j) {
                    int b = b0 + j;
                    v[j] = f2bf(ax*MsT[4*b+1][row] + ay*MsT[4*b+2][row] + az*MsT[4*b+3][row]);
                }
            } else {
                #pragma unroll
                for (int j = 0; j < 8; ++j) v[j] = 0;
            }
            *(bf16x8*)&Asl[buf][cell * 8] = v;
        }
    };
    auto stageB = [&](int kt, int buf) {   // 2 gl_lds per thread
        #pragma unroll
        for (int p = 0; p < 2; ++p) {
            int cell = p * 256 + t;
            int k8 = cell >> 7, col = cell & 127;
            const short* src = W1t + (size_t)(col0 + col) * K1P + kt*32 + k8*8;
            gl_lds16(src, &Bsl[buf][(p * 256 + w * 64) * 8]);
        }
    };

    f32x4 acc[4][4] = {};
    const int NS = K1P / 32;   // 9
    stageA(0, 0);
    stageB(0, 0); stageB(1, 1); stageB(2, 2);   // 6 B-loads in flight

    #pragma unroll
    for (int s = 0; s < NS; ++s) {
        if (s <= NS - 3)      asm volatile("s_waitcnt vmcnt(4) lgkmcnt(0)\n\ts_barrier" ::: "memory");
        else if (s == NS - 2) asm volatile("s_waitcnt vmcnt(2) lgkmcnt(0)\n\ts_barrier" ::: "memory");
        else                  asm volatile("s_waitcnt vmcnt(0) lgkmcnt(0)\n\ts_barrier" ::: "memory");
        if (s + 3 < NS) stageB(s + 3, (s + 3) & 3);
        bf16x8 af[4], bfr[4];
        #pragma unroll
        for (int m = 0; m < 4; ++m)
            af[m] = *(const bf16x8*)&Asl[s & 1][(lg*128 + wr*64 + m*16 + li) * 8];
        #pragma unroll
        for (int n = 0; n < 4; ++n)
            bfr[n] = *(const bf16x8*)&Bsl[s & 3][(lg*128 + wc*64 + n*16 + li) * 8];
        if (s + 1 < NS) stageA(s + 1, (s + 1) & 1);
        __builtin_amdgcn_s_setprio(1);
        #pragma unroll
        for (int m = 0; m < 4; ++m)
            #pragma unroll
            for (int n = 0; n < 4; ++n)
                acc[m][n] = __builtin_amdgcn_mfma_f32_16x16x32_bf16(af[m], bfr[n], acc[m][n], 0, 0, 0);
        __builtin_amdgcn_s_setprio(0);
    }

    float bv[4];
    #pragma unroll
    for (int n = 0; n < 4; ++n) bv[n] = bias[col0 + wc*64 + n*16 + li];
    #pragma unroll
    for (int m = 0; m < 4; ++m)
        #pragma unroll
        for (int r = 0; r < 4; ++r) {
            int row = row0 + wr*64 + m*16 + lg*4 + r;
            if (row >= M) continue;
            size_t base = (size_t)row * HID + col0 + wc*64 + li;
            #pragma unroll
            for (int n = 0; n < 4; ++n) {
                float cx = acc[m][n][r] + bv[n];
                C[base + n*16] = f2bf(silu(cx));
            }
        }
}

// ============ GEMM2: 128x128, BK=32, 4-buf deep pipeline + fused energy ============
__global__ __launch_bounds__(256, 2) void gemm2_mfma(
    const short* __restrict__ A, const short* __restrict__ W2t,
    const float* __restrict__ bias, const float* __restrict__ W3,
    const float* __restrict__ b3, const float* __restrict__ scale,
    const float* __restrict__ shift, const int* __restrict__ Z,
    float* __restrict__ out, int M, int nwg)
{
    __shared__ short Asl[4][4096];     // 4x8KB
    __shared__ short Bsl[4][4096];     // 4x8KB
    __shared__ float rsum[2][128];
    __shared__ float red[4];
    int t = threadIdx.x;
    int w = t >> 6, lane = t & 63;
    int wr = w >> 1, wc = w & 1;
    int li = lane & 15, lg = lane >> 4;
    int lin = xcd_swz(blockIdx.x, nwg);
    int row0 = (lin >> 2) * 128;
    int col0 = (lin & 3) * 128;

    auto stage = [&](int kt, int buf) {   // 4 gl_lds per thread (2 A + 2 B)
        #pragma unroll
        for (int p = 0; p < 2; ++p) {
            int cell = p * 256 + t;
            int k8 = cell >> 7, row = cell & 127;
            int gr = row0 + row; if (gr > M - 1) gr = M - 1;
            const short* src = A + (size_t)gr * HID + kt*32 + k8*8;
            gl_lds16(src, &Asl[buf][(p * 256 + w * 64) * 8]);
        }
        #pragma unroll
        for (int p = 0; p < 2; ++p) {
            int cell = p * 256 + t;
            int k8 = cell >> 7, col = cell & 127;
            const short* src = W2t + (size_t)(col0 + col) * HID + kt*32 + k8*8;
            gl_lds16(src, &Bsl[buf][(p * 256 + w * 64) * 8]);
        }
    };

    f32x4 acc[4][4] = {};
    const int NS = HID / 32;   // 16
    stage(0, 0); stage(1, 1); stage(2, 2);   // 12 loads in flight

    for (int s = 0; s < NS; ++s) {
        if (s <= NS - 3)      asm volatile("s_waitcnt vmcnt(8)\n\ts_barrier" ::: "memory");
        else if (s == NS - 2) asm volatile("s_waitcnt vmcnt(4)\n\ts_barrier" ::: "memory");
        else                  asm volatile("s_waitcnt vmcnt(0)\n\ts_barrier" ::: "memory");
        if (s + 3 < NS) stage(s + 3, (s + 3) & 3);
        bf16x8 af[4], bfr[4];
        #pragma unroll
        for (int m = 0; m < 4; ++m)
            af[m] = *(const bf16x8*)&Asl[s & 3][(lg*128 + wr*64 + m*16 + li) * 8];
        #pragma unroll
        for (int n = 0; n < 4; ++n)
            bfr[n] = *(const bf16x8*)&Bsl[s & 3][(lg*128 + wc*64 + n*16 + li) * 8];
        __builtin_amdgcn_s_setprio(1);
        #pragma unroll
        for (int m = 0; m < 4; ++m)
            #pragma unroll
            for (int n = 0; n < 4; ++n)
                acc[m][n] = __builtin_amdgcn_mfma_f32_16x16x32_bf16(af[m], bfr[n], acc[m][n], 0, 0, 0);
        __builtin_amdgcn_s_setprio(0);
    }

    // fused epilogue: silu + W3 dot + scale/shift + block energy sum
    float bv[4], w3v[4];
    #pragma unroll
    for (int n = 0; n < 4; ++n) {
        int col = col0 + wc*64 + n*16 + li;
        bv[n]  = bias[col];
        w3v[n] = W3[col];
    }
    #pragma unroll
    for (int m = 0; m < 4; ++m)
        #pragma unroll
        for (int r = 0; r < 4; ++r) {
            float s = 0.f;
            #pragma unroll
            for (int n = 0; n < 4; ++n) {
                float cx = acc[m][n][r] + bv[n];
                s += silu(cx) * w3v[n];
            }
            #pragma unroll
            for (int off = 1; off < 16; off <<= 1) s += __shfl_xor(s, off);
            if (li == 0) rsum[wc][wr*64 + m*16 + lg*4 + r] = s;
        }
    __syncthreads();
    float e = 0.f;
    if (t < 128) {
        int row = row0 + t;
        if (row < M) {
            float v = rsum[0][t] + rsum[1][t];
            int z = Z[row];
            e = scale[z] * v;
            if ((lin & 3) == 0) e += scale[z] * b3[0] + shift[z];
        }
    }
    #pragma unroll
    for (int off = 32; off > 0; off >>= 1) e += __shfl_down(e, off);
    if (lane == 0) red[w] = e;
    __syncthreads();
    if (t == 0) atomicAdd(out, red[0] + red[1] + red[2] + red[3]);
}

extern "C" void kernel_launch(void* const* d_in, const int* in_sizes, int n_in,
                              void* d_out, int out_size, void* d_ws, size_t ws_size,
                              hipStream_t stream)
{
    const float* R       = (const float*)d_in[0];
    const int*   Z       = (const int*)  d_in[1];
    const int*   idx     = (const int*)  d_in[2];
    const float* centers = (const float*)d_in[5];
    const float* width   = (const float*)d_in[6];
    const float* W1      = (const float*)d_in[7];
    const float* b1      = (const float*)d_in[8];
    const float* W2      = (const float*)d_in[9];
    const float* b2      = (const float*)d_in[10];
    const float* W3      = (const float*)d_in[11];
    const float* b3      = (const float*)d_in[12];
    const float* scale   = (const float*)d_in[13];
    const float* shift   = (const float*)d_in[14];

    int nAtoms = in_sizes[0] / 3;
    int nEdges = in_sizes[2] / 2;

    size_t m0m1_b = (size_t)nAtoms * 64 * sizeof(float);   // 25.6 MB
    size_t h1_b   = (size_t)nAtoms * HID * 2;              // 102.4 MB
    size_t w1t_b  = (size_t)HID * K1P * 2;                 // 288 KB
    size_t w2t_b  = (size_t)HID * HID * 2;                 // 512 KB
    if (ws_size < m0m1_b + h1_b + w1t_b + w2t_b) return;

    char* ws = (char*)d_ws;
    float* M0M1 = (float*)ws;
    char*  regB = ws + m0m1_b;
    short* h1   = (short*)regB;
    short* W1t  = (short*)(ws + m0m1_b + h1_b);
    short* W2t  = W1t + (size_t)HID * K1P;

    int nb = (nAtoms + 1023) / 1024;
    size_t sorted_b = (size_t)nEdges * sizeof(float4);
    float4* sorted = (float4*)regB;
    int* counts   = (int*)(regB + sorted_b);
    int* starts   = counts + nAtoms;
    int* cursor   = starts + nAtoms + 1;
    int* blockSum = cursor + nAtoms;
    int* blockOff = blockSum + nb;
    if (sorted_b + (size_t)(3 * nAtoms + 1 + 2 * nb) * sizeof(int) > h1_b) return;

    float* out = (float*)d_out;

    hipMemsetAsync(counts, 0, (size_t)nAtoms * sizeof(int), stream);
    hipMemsetAsync(out, 0, sizeof(float), stream);

    convW_kernel<<<dim3(2, K1P), 256, 0, stream>>>(W1, W1t, 272, K1P, HID);
    convW_kernel<<<dim3(2, HID), 256, 0, stream>>>(W2, W2t, HID, HID, HID);

    int eb = (nEdges + 255) / 256;
    hist_kernel <<<eb, 256, 0, stream>>>(idx, counts, nEdges);
    scan1_kernel<<<nb, 1024, 0, stream>>>(counts, starts, blockSum, nAtoms);
    scan2_kernel<<<1, 1024, 0, stream>>>(blockSum, blockOff, starts, nb, nAtoms);
    scan3_kernel<<<nb, 1024, 0, stream>>>(starts, cursor, blockOff, nAtoms);
    scatter_kernel<<<eb, 256, 0, stream>>>(R, idx, cursor, sorted, nEdges);
    accum_kernel<<<(nAtoms + 3) / 4, 256, 0, stream>>>(sorted, starts, centers, width, M0M1, nAtoms);

    int gb = (nAtoms + 127) / 128;   // 782 row-blocks
    int nwg = gb * 4;                // x4 col-blocks, col-fast in lin order
    gemm1_mfma<<<nwg, 256, 0, stream>>>(M0M1, W1t, b1, h1, nAtoms, nwg);
    gemm2_mfma<<<nwg, 256, 0, stream>>>(h1, W2t, b2, W3, b3, scale, shift, Z, out, nAtoms, nwg);
}